// Round 11
// baseline (277.153 us; speedup 1.0000x reference)
//
#include <hip/hip_runtime.h>
#include <cfloat>

#define N_PTS 8192
#define DTOK 256
#define KNN 16

typedef __attribute__((ext_vector_type(8))) short short8;
typedef __attribute__((ext_vector_type(4))) float float4v;
typedef __attribute__((ext_vector_type(2))) float float2v;

__device__ inline short f2bf(float f) {   // RTNE fp32 -> bf16
  unsigned u = __float_as_uint(f);
  u += 0x7fffu + ((u >> 16) & 1u);
  return (short)(u >> 16);
}
__device__ inline float bf2f(short h) {
  return __uint_as_float(((unsigned)(unsigned short)h) << 16);
}

// ---------------------------------------------------------------------------
// MERGED prologue kernel (R9): knn_prep + convert_w(a) + convert_w(b).
// ---------------------------------------------------------------------------
__global__ __launch_bounds__(256) void prep_convert_kernel(
    const float* __restrict__ xyz, float4* __restrict__ xyz4,
    const float* __restrict__ W1a, short* __restrict__ bhiA,
    short* __restrict__ bloA, const float* __restrict__ W1b,
    short* __restrict__ bhiB, short* __restrict__ bloB) {
  const int b = blockIdx.x;      // 0..1023
  const int k = threadIdx.x;     // 0..255

  if (b < 32) {                  // xyz4 prep (exact knn_prep rounding)
    const int i = b * 256 + k;
    float x = xyz[3 * i], y = xyz[3 * i + 1], z = xyz[3 * i + 2];
    float sq = __fadd_rn(__fadd_rn(__fmul_rn(x, x), __fmul_rn(y, y)),
                         __fmul_rn(z, z));
    xyz4[i] = make_float4(x, y, z, sq);
  }

  const int n = b & 511;         // 0..511
  const float* W1 = (b < 512) ? W1a : W1b;
  short* bhi = (b < 512) ? bhiA : bhiB;
  short* blo = (b < 512) ? bloA : bloB;
  const float v = (n < 256) ? W1[k * DTOK + n]
                            : W1[(259 + k) * DTOK + (n - 256)];
  short h = f2bf(v);
  bhi[n * 256 + k] = h;
  blo[n * 256 + k] = f2bf(v - bf2f(h));
}

// ---------------------------------------------------------------------------
// KNN v13: SUBSET-THRESHOLD pass A + v12 pass B (compact-then-rank).
// R10 post-mortem: v12's compact removed the insert chains but pass A (LDS-
// staged full 8192-stream, 16 barriers) was the remaining ~half of the 40us.
// v13: t is derived from the SUBSET j in [0,2048) only -- a subset's 16th-
// smallest lane-min is PROVABLY >= the global 16th-smallest distance (the 16
// smallest lane-mins are 16 distinct candidates with d <= t), so prune-
// safety holds for any subset and nbr is bit-identical for any valid t
// (pass B rank-select is exact over survivors; non-survivors have global
// rank >= 16). Pass A becomes a 32-iter stream over a 32KB L1-resident
// window: no LDS staging, no barriers. Looser t only raises survivor count
// (expected ~74/query << CAP=256; compress16 is the exact cold fallback).
// Self-fix kept in pass A (needed for bound validity when self is in the
// subset; auto no-op for i >= 2048). Distance chain unchanged op-for-op.
// ---------------------------------------------------------------------------
#define CAP 256                     // survivor buffer capacity per query

// Cold path: compress buffer to its top-16 by (d,j) rank. Reads all precede
// writes (wave in-order issue); exact: discarded entries can't be in the
// global top-16 (all lex-smaller elements are already in the buffer).
__device__ inline void compress16(float* bD, int* bJ, int& cnt, int lane) {
  float kd[4]; int kj[4], kr[4]; int nk = 0;
  for (int s = lane; s < cnt; s += 64) {
    const float ds = bD[s]; const int js = bJ[s];
    int r = 0;
    for (int k = 0; k < cnt; ++k) {
      const float dk = bD[k]; const int jk = bJ[k];
      r += (dk < ds) || (dk == ds && jk < js);
    }
    if (r < 16) { kd[nk] = ds; kj[nk] = js; kr[nk] = r; ++nk; }
  }
  for (int e = 0; e < nk; ++e) { bD[kr[e]] = kd[e]; bJ[kr[e]] = kj[e]; }
  cnt = 16;
}

__global__ __launch_bounds__(256) void knn_select_kernel(
    const float4* __restrict__ xyz4, int* __restrict__ nbr) {
  __shared__ float bufD[4][2][CAP];   // survivor distances, 8 KB
  __shared__ int   bufJ[4][2][CAP];   // survivor indices,   8 KB
  const int tid = threadIdx.x;
  const int lane = tid & 63;
  const int wave = tid >> 6;
  const int i0 = blockIdx.x * 8 + wave * 2;
  const int i1 = i0 + 1;

  const float4 q0 = xyz4[i0];
  const float4 q1 = xyz4[i1];

  const int il0 = i0 & 63, il1 = i1 & 63;   // uniform
  const int gself = i0 >> 6;                // uniform: 64-group of i0,i1

  // ---- pass A: lane-mins over SUBSET j<2048 (32 KB, L1-resident) ----
  float lm0 = FLT_MAX, lm1 = FLT_MAX;
  {
    float4 pc = xyz4[lane];               // group 0 prefetch
    #pragma unroll 2
    for (int grp = 0; grp < 32; ++grp) {
      float4 pn;
      if (grp < 31) pn = xyz4[(grp + 1) * 64 + lane];
      const float dot0 = fmaf(q0.z, pc.z, fmaf(q0.y, pc.y,
                                               __fmul_rn(q0.x, pc.x)));
      float d0 = __fadd_rn(__fmaf_rn(-2.0f, dot0, q0.w), pc.w);
      const float dot1 = fmaf(q1.z, pc.z, fmaf(q1.y, pc.y,
                                               __fmul_rn(q1.x, pc.x)));
      float d1 = __fadd_rn(__fmaf_rn(-2.0f, dot1, q1.w), pc.w);
      if (grp == gself) {                 // uniform; required for bound
        if (lane == il0) d0 = __fadd_rn(d0, 1e10f);
        if (lane == il1) d1 = __fadd_rn(d1, 1e10f);
      }
      lm0 = fminf(lm0, d0);
      lm1 = fminf(lm1, d1);
      pc = pn;
    }
  }

  // ---- two interleaved 64-lane bitonic sorts (ascending) of lane-mins ----
  float v0 = lm0;
  float v1 = lm1;
  #pragma unroll
  for (int k = 2; k <= 64; k <<= 1) {
    #pragma unroll
    for (int j = k >> 1; j > 0; j >>= 1) {
      const float o0 = __shfl_xor(v0, j, 64);
      const float o1 = __shfl_xor(v1, j, 64);
      const bool keepmin = ((lane & k) == 0) == ((lane & j) == 0);
      v0 = keepmin ? fminf(v0, o0) : fmaxf(v0, o0);
      v1 = keepmin ? fminf(v1, o1) : fmaxf(v1, o1);
    }
  }
  const float t0 = __shfl(v0, 15, 64);  // >= true 16th-smallest dist (q0)
  const float t1 = __shfl(v1, 15, 64);  // >= true 16th-smallest dist (q1)

  // ---- pass B: global stream (L2-resident) + compact survivors to LDS ----
  float* bD0 = bufD[wave][0]; int* bJ0 = bufJ[wave][0];
  float* bD1 = bufD[wave][1]; int* bJ1 = bufJ[wave][1];
  int cnt0 = 0, cnt1 = 0;                       // wave-uniform
  const unsigned long long lml = (1ull << lane) - 1;   // lanemask_lt

  float4 pc = xyz4[lane];               // group 0 prefetch
  #pragma unroll 2
  for (int grp = 0; grp < N_PTS / 64; ++grp) {
    float4 pn;
    if (grp < N_PTS / 64 - 1) pn = xyz4[(grp + 1) * 64 + lane];

    const float dot0 = fmaf(q0.z, pc.z, fmaf(q0.y, pc.y,
                                             __fmul_rn(q0.x, pc.x)));
    float d0 = __fadd_rn(__fmaf_rn(-2.0f, dot0, q0.w), pc.w);
    const float dot1 = fmaf(q1.z, pc.z, fmaf(q1.y, pc.y,
                                             __fmul_rn(q1.x, pc.x)));
    float d1 = __fadd_rn(__fmaf_rn(-2.0f, dot1, q1.w), pc.w);
    if (grp == gself) {                 // uniform rare branch
      if (lane == il0) d0 = __fadd_rn(d0, 1e10f);
      if (lane == il1) d1 = __fadd_rn(d1, 1e10f);
    }

    const unsigned long long m0 = __ballot(d0 <= t0);
    if (m0) {                           // wave-uniform skip
      if (d0 <= t0) {
        const int p = cnt0 + (int)__popcll(m0 & lml);
        bD0[p] = d0; bJ0[p] = grp * 64 + lane;
      }
      cnt0 += (int)__popcll(m0);
      if (cnt0 > CAP - 64) compress16(bD0, bJ0, cnt0, lane);  // cold
    }
    const unsigned long long m1 = __ballot(d1 <= t1);
    if (m1) {                           // wave-uniform skip
      if (d1 <= t1) {
        const int p = cnt1 + (int)__popcll(m1 & lml);
        bD1[p] = d1; bJ1[p] = grp * 64 + lane;
      }
      cnt1 += (int)__popcll(m1);
      if (cnt1 > CAP - 64) compress16(bD1, bJ1, cnt1, lane);  // cold
    }
    pc = pn;
  }

  // ---- epilogue: rank-select top-16 by lexicographic (d, j) ----
  for (int s = lane; s < cnt0; s += 64) {
    const float ds = bD0[s]; const int js = bJ0[s];
    int r = 0;
    for (int k = 0; k < cnt0; ++k) {    // broadcast LDS reads
      const float dk = bD0[k]; const int jk = bJ0[k];
      r += (dk < ds) || (dk == ds && jk < js);
    }
    if (r < 16) nbr[i0 * KNN + r] = js;
  }
  for (int s = lane; s < cnt1; s += 64) {
    const float ds = bD1[s]; const int js = bJ1[s];
    int r = 0;
    for (int k = 0; k < cnt1; ++k) {
      const float dk = bD1[k]; const int jk = bJ1[k];
      r += (dk < ds) || (dk == ds && jk < js);
    }
    if (r < 16) nbr[i1 * KNN + r] = js;
  }
}

// ---------------------------------------------------------------------------
// pq GEMM v2 (frozen).
// ---------------------------------------------------------------------------
__global__ __launch_bounds__(256, 2) void pq_gemm_fused_kernel(
    const float* __restrict__ A, const short* __restrict__ Bthi,
    const short* __restrict__ Btlo, const float* __restrict__ xyz,
    const float* __restrict__ W1, const float* __restrict__ b1,
    float* __restrict__ R, float* __restrict__ Q) {
  __shared__ short Ahi[64][32], Alo[64][32];    // 4K + 4K
  __shared__ short Bhi[128][32], Blo[128][32];  // 8K + 8K
  __shared__ float Qs[64][65];                  // 16.6K
  __shared__ float sx[64][3];
  __shared__ float swz[6][64];
  __shared__ float sb1[64];

  const int tid = threadIdx.x;
  const int lane = tid & 63;
  const int wave = tid >> 6;
  const int l15 = lane & 15;
  const int quad = lane >> 4;
  const int mh = wave & 1;
  const int qh = wave >> 1;
  const int m0 = blockIdx.x * 64;
  const int np0 = blockIdx.y * 64;

  if (tid < 64) {
    sx[tid][0] = xyz[(m0 + tid) * 3];
    sx[tid][1] = xyz[(m0 + tid) * 3 + 1];
    sx[tid][2] = xyz[(m0 + tid) * 3 + 2];
  } else if (tid < 128) {
    int n = tid - 64;
    sb1[n] = b1[np0 + n];
    #pragma unroll
    for (int r = 0; r < 3; ++r) {
      swz[r][n] = W1[(256 + r) * DTOK + np0 + n];
      swz[3 + r][n] = W1[(515 + r) * DTOK + np0 + n];
    }
  }

  float4v acc[2][4];
  #pragma unroll
  for (int mf = 0; mf < 2; ++mf)
    #pragma unroll
    for (int nf = 0; nf < 4; ++nf)
      #pragma unroll
      for (int e = 0; e < 4; ++e) acc[mf][nf][e] = 0.f;

  const int ar = tid >> 2;             // A staging row 0..63
  const int ak = (tid & 3) * 8;        // A staging k-offset

  #pragma unroll 1
  for (int kc = 0; kc < 8; ++kc) {
    const int k0 = kc * 32;
    __syncthreads();
    {
      const float* asrc = A + (size_t)(m0 + ar) * 256 + k0 + ak;
      float4 a0 = *(const float4*)asrc;
      float4 a1 = *(const float4*)(asrc + 4);
      float v[8] = {a0.x, a0.y, a0.z, a0.w, a1.x, a1.y, a1.z, a1.w};
      short8 h8, l8;
      #pragma unroll
      for (int e = 0; e < 8; ++e) {
        short h = f2bf(v[e]);
        h8[e] = h;
        l8[e] = f2bf(v[e] - bf2f(h));
      }
      *(short8*)(&Ahi[ar][ak]) = h8;
      *(short8*)(&Alo[ar][ak]) = l8;
    }
    #pragma unroll
    for (int l = 0; l < 4; ++l) {
      const int rem = tid + 256 * (l & 1);
      const int row = rem >> 2;
      const int koff = (rem & 3) * 8;
      const int n = (row < 64) ? (np0 + row) : (256 + np0 + row - 64);
      const short* src = ((l < 2) ? Bthi : Btlo) + (size_t)n * 256 + k0 + koff;
      short8 vv = *(const short8*)src;
      if (l < 2) *(short8*)(&Bhi[row][koff]) = vv;
      else       *(short8*)(&Blo[row][koff]) = vv;
    }
    __syncthreads();

    short8 ah[2], al[2], bh[4], bl[4];
    #pragma unroll
    for (int mf = 0; mf < 2; ++mf) {
      ah[mf] = *(const short8*)(&Ahi[mh * 32 + mf * 16 + l15][quad * 8]);
      al[mf] = *(const short8*)(&Alo[mh * 32 + mf * 16 + l15][quad * 8]);
    }
    #pragma unroll
    for (int nf = 0; nf < 4; ++nf) {
      bh[nf] = *(const short8*)(&Bhi[qh * 64 + nf * 16 + l15][quad * 8]);
      bl[nf] = *(const short8*)(&Blo[qh * 64 + nf * 16 + l15][quad * 8]);
    }
    #pragma unroll
    for (int mf = 0; mf < 2; ++mf)
      #pragma unroll
      for (int nf = 0; nf < 4; ++nf) {
        acc[mf][nf] = __builtin_amdgcn_mfma_f32_16x16x32_bf16(
            ah[mf], bh[nf], acc[mf][nf], 0, 0, 0);
        acc[mf][nf] = __builtin_amdgcn_mfma_f32_16x16x32_bf16(
            ah[mf], bl[nf], acc[mf][nf], 0, 0, 0);
        acc[mf][nf] = __builtin_amdgcn_mfma_f32_16x16x32_bf16(
            al[mf], bh[nf], acc[mf][nf], 0, 0, 0);
      }
  }

  if (qh == 1) {
    #pragma unroll
    for (int mf = 0; mf < 2; ++mf)
      #pragma unroll
      for (int nf = 0; nf < 4; ++nf)
        #pragma unroll
        for (int e = 0; e < 4; ++e) {
          int row = mh * 32 + mf * 16 + quad * 4 + e;
          int col = nf * 16 + l15;
          float q = acc[mf][nf][e] + sx[row][0] * swz[3][col] +
                    sx[row][1] * swz[4][col] + sx[row][2] * swz[5][col];
          Qs[row][col] = q;
          Q[(size_t)(m0 + row) * DTOK + np0 + col] = q;
        }
  }
  __syncthreads();
  if (qh == 0) {
    #pragma unroll
    for (int mf = 0; mf < 2; ++mf)
      #pragma unroll
      for (int nf = 0; nf < 4; ++nf)
        #pragma unroll
        for (int e = 0; e < 4; ++e) {
          int row = mh * 32 + mf * 16 + quad * 4 + e;
          int col = nf * 16 + l15;
          float p = acc[mf][nf][e] + sx[row][0] * swz[0][col] +
                    sx[row][1] * swz[1][col] + sx[row][2] * swz[2][col];
          R[(size_t)(m0 + row) * DTOK + np0 + col] =
              (p + sb1[col]) - Qs[row][col];
        }
  }
}

// ---------------------------------------------------------------------------
// EdgeConv via MFMA (frozen R10 version).
// ---------------------------------------------------------------------------
#define EP 8          // points per group

__global__ __launch_bounds__(256, 2) void edge_mfma_kernel(
    const float* __restrict__ R, const float* __restrict__ Q,
    const int* __restrict__ nbr, const float* __restrict__ W2,
    const float* __restrict__ b2, float* __restrict__ out,
    int num_groups, int groups_per_block) {
  __shared__ short Hs[EP * KNN * DTOK];   // 128 rows x 256, 64 KB
  const int lane = threadIdx.x & 63;
  const int wave = threadIdx.x >> 6;
  const int l15 = lane & 15;
  const int quad = lane >> 4;

  short8 bfr[4][8];
  #pragma unroll
  for (int nt_i = 0; nt_i < 4; ++nt_i) {
    const int n = (wave * 4 + nt_i) * 16 + l15;
    #pragma unroll
    for (int kt = 0; kt < 8; ++kt) {
      short8 f;
      #pragma unroll
      for (int jj = 0; jj < 8; ++jj) {
        int k = kt * 32 + quad * 8 + jj;
        f[jj] = f2bf(W2[k * DTOK + n]);
      }
      bfr[nt_i][kt] = f;
    }
  }

  const int wc8 = lane >> 1;
  const int wsub = (lane & 1) * 4;

  for (int gi = 0; gi < groups_per_block; ++gi) {
    const int g = blockIdx.x + gi * gridDim.x;
    if (g >= num_groups) break;
    const int i0 = g * EP;

    // ---- build H: prefetched nbr via lane reg + shfl, pipelined gathers ----
    {
      const int ia = i0 + wave * 2;
      const int jr0 = nbr[ia * KNN + l15];
      const int jr1 = nbr[(ia + 1) * KNN + l15];
      const float4 ri0 = ((const float4*)(R + (size_t)ia * DTOK))[lane];
      const float4 ri1 = ((const float4*)(R + (size_t)(ia + 1) * DTOK))[lane];
      #pragma unroll
      for (int pp = 0; pp < 2; ++pp) {
        const float4 ri = pp ? ri1 : ri0;
        const int jr = pp ? jr1 : jr0;
        #pragma unroll
        for (int k = 0; k < KNN; ++k) {
          const int j = __shfl(jr, k, 16);
          const float4 qj = ((const float4*)(Q + (size_t)j * DTOK))[lane];
          const int r = wave * 32 + pp * 16 + k;
          uint2 pk;
          pk.x = ((unsigned)(unsigned short)f2bf(fmaxf(ri.x + qj.x, 0.f))) |
                 (((unsigned)(unsigned short)f2bf(fmaxf(ri.y + qj.y, 0.f))) << 16);
          pk.y = ((unsigned)(unsigned short)f2bf(fmaxf(ri.z + qj.z, 0.f))) |
                 (((unsigned)(unsigned short)f2bf(fmaxf(ri.w + qj.w, 0.f))) << 16);
          *(uint2*)(&Hs[r * DTOK + ((wc8 ^ (r & 7)) << 3) + wsub]) = pk;
        }
      }
    }
    __syncthreads();

    #pragma unroll
    for (int mp = 0; mp < 4; ++mp) {
      float4v acc[2][4];
      #pragma unroll
      for (int mi = 0; mi < 2; ++mi)
        #pragma unroll
        for (int nt_i = 0; nt_i < 4; ++nt_i)
          #pragma unroll
          for (int e = 0; e < 4; ++e) acc[mi][nt_i][e] = 0.f;

      #pragma unroll
      for (int kt = 0; kt < 8; ++kt) {
        const int pc = ((kt * 4 + quad) ^ (l15 & 7)) << 3;
        const short8 a0 = *(const short8*)(
            &Hs[((mp * 2 + 0) * 16 + l15) * DTOK + pc]);
        const short8 a1 = *(const short8*)(
            &Hs[((mp * 2 + 1) * 16 + l15) * DTOK + pc]);
        #pragma unroll
        for (int nt_i = 0; nt_i < 4; ++nt_i) {
          acc[0][nt_i] = __builtin_amdgcn_mfma_f32_16x16x32_bf16(
              a0, bfr[nt_i][kt], acc[0][nt_i], 0, 0, 0);
          acc[1][nt_i] = __builtin_amdgcn_mfma_f32_16x16x32_bf16(
              a1, bfr[nt_i][kt], acc[1][nt_i], 0, 0, 0);
        }
      }

      #pragma unroll
      for (int mi = 0; mi < 2; ++mi) {
        #pragma unroll
        for (int nt_i = 0; nt_i < 4; ++nt_i) {
          float rm = fmaxf(fmaxf(acc[mi][nt_i][0], acc[mi][nt_i][1]),
                           fmaxf(acc[mi][nt_i][2], acc[mi][nt_i][3]));
          rm = fmaxf(rm, __shfl_xor(rm, 16, 64));
          rm = fmaxf(rm, __shfl_xor(rm, 32, 64));
          if (lane < 16) {
            const int i = i0 + mp * 2 + mi;
            const int n = (wave * 4 + nt_i) * 16 + lane;
            out[(size_t)i * DTOK + n] = rm + b2[n];
          }
        }
      }
    }
    __syncthreads();
  }
}

// ---------------------------------------------------------------------------
extern "C" void kernel_launch(void* const* d_in, const int* in_sizes, int n_in,
                              void* d_out, int out_size, void* d_ws,
                              size_t ws_size, hipStream_t stream) {
  const float* xyz = (const float*)d_in[0];
  const float* feat = (const float*)d_in[1];
  const float* W1a = (const float*)d_in[2];
  const float* b1a = (const float*)d_in[3];
  const float* W2a = (const float*)d_in[4];
  const float* b2a = (const float*)d_in[5];
  const float* W1b = (const float*)d_in[6];
  const float* b1b = (const float*)d_in[7];
  const float* W2b = (const float*)d_in[8];
  const float* b2b = (const float*)d_in[9];
  float* out = (float*)d_out;

  // ws layout (~25 MB): nbr 0.5 | xyz4 128KB | Bt_b @w1+1MB (512KB, in the
  // free w1+[128KB,8MB) gap) | R @w1+8MB | Q @w1+16MB | Bt_a @w1+24MB
  char* w = (char*)d_ws;
  const size_t SZ_NBR = (size_t)N_PTS * KNN * sizeof(int);        // 512 KB
  const size_t MB = 1024 * 1024;
  int* nbr = (int*)w;
  char* w1 = w + SZ_NBR;
  float4* xyz4 = (float4*)w1;                  // 128 KB
  short* BthiB = (short*)(w1 + 1 * MB);        // 256 KB (free region)
  short* BtloB = BthiB + 512 * 256;            // 256 KB
  float* R = (float*)(w1 + 8 * MB);            // 8 MB
  float* Q = (float*)(w1 + 16 * MB);           // 8 MB
  short* BthiA = (short*)(w1 + 24 * MB);       // 256 KB
  short* BtloA = BthiA + 512 * 256;            // 256 KB
  float* bufC = out;                           // layer-a output staging

  const int num_groups = N_PTS / EP;           // 1024
  const int nblocks = 512;

  // merged prologue: xyz4 prep + both weight conversions (one dispatch)
  prep_convert_kernel<<<1024, 256, 0, stream>>>(
      xyz, xyz4, W1a, BthiA, BtloA, W1b, BthiB, BtloB);

  knn_select_kernel<<<N_PTS / 8, 256, 0, stream>>>(xyz4, nbr);

  // layer a
  pq_gemm_fused_kernel<<<dim3(N_PTS / 64, 4), 256, 0, stream>>>(
      feat, BthiA, BtloA, xyz, W1a, b1a, R, Q);
  edge_mfma_kernel<<<nblocks, 256, 0, stream>>>(R, Q, nbr, W2a, b2a, bufC,
                                                num_groups, 2);

  // layer b
  pq_gemm_fused_kernel<<<dim3(N_PTS / 64, 4), 256, 0, stream>>>(
      bufC, BthiB, BtloB, xyz, W1b, b1b, R, Q);
  edge_mfma_kernel<<<nblocks, 256, 0, stream>>>(R, Q, nbr, W2b, b2b, out,
                                                num_groups, 2);
}

// Round 12
// 228.152 us; speedup vs baseline: 1.2148x; 1.2148x over previous
//
#include <hip/hip_runtime.h>
#include <cfloat>

#define N_PTS 8192
#define DTOK 256
#define KNN 16

typedef __attribute__((ext_vector_type(8))) short short8;
typedef __attribute__((ext_vector_type(4))) float float4v;
typedef __attribute__((ext_vector_type(2))) float float2v;

__device__ inline short f2bf(float f) {   // RTNE fp32 -> bf16
  unsigned u = __float_as_uint(f);
  u += 0x7fffu + ((u >> 16) & 1u);
  return (short)(u >> 16);
}
__device__ inline float bf2f(short h) {
  return __uint_as_float(((unsigned)(unsigned short)h) << 16);
}

// ---- VOP3P packed fp32 helpers: 2 IEEE-RN fp32 ops per issue slot --------
__device__ inline float2v pk_mul(float2v a, float2v b) {
  float2v d;
  asm("v_pk_mul_f32 %0, %1, %2" : "=v"(d) : "v"(a), "v"(b));
  return d;
}
__device__ inline float2v pk_fma(float2v a, float2v b, float2v c) {
  float2v d;
  asm("v_pk_fma_f32 %0, %1, %2, %3" : "=v"(d) : "v"(a), "v"(b), "v"(c));
  return d;
}
__device__ inline float2v pk_add(float2v a, float2v b) {
  float2v d;
  asm("v_pk_add_f32 %0, %1, %2" : "=v"(d) : "v"(a), "v"(b));
  return d;
}

// Serial stable top-16 insert for one 64-candidate group (proven v5 code).
__device__ inline void insert_group(float d, int base, float t, int lane,
                                    float& sd, int& sj, float& s15) {
  unsigned long long m = __ballot(d <= t);
  while (m) {                          // m is wave-uniform
    const int src = __ffsll(m) - 1;    // ascending lane == ascending j
    m &= m - 1;
    const float dc = __shfl(d, src);
    if (dc < s15) {                    // recheck vs running bound
      const int jc = base + src;
      const unsigned long long bm = __ballot(sd <= dc) & 0xFFFFull;
      const int pos = (int)__popcll(bm);      // stable position
      const float pu = __shfl_up(sd, 1);
      const int ju = __shfl_up(sj, 1);
      if (lane < 16) {
        if (lane > pos)        { sd = pu; sj = ju; }
        else if (lane == pos)  { sd = dc; sj = jc; }
      }
      s15 = __shfl(sd, 15);
    }
  }
}

// ---------------------------------------------------------------------------
// MERGED prologue kernel (R9): knn_prep + convert_w(a) + convert_w(b).
// ---------------------------------------------------------------------------
__global__ __launch_bounds__(256) void prep_convert_kernel(
    const float* __restrict__ xyz, float4* __restrict__ xyz4,
    const float* __restrict__ W1a, short* __restrict__ bhiA,
    short* __restrict__ bloA, const float* __restrict__ W1b,
    short* __restrict__ bhiB, short* __restrict__ bloB) {
  const int b = blockIdx.x;      // 0..1023
  const int k = threadIdx.x;     // 0..255

  if (b < 32) {                  // xyz4 prep (exact knn_prep rounding)
    const int i = b * 256 + k;
    float x = xyz[3 * i], y = xyz[3 * i + 1], z = xyz[3 * i + 2];
    float sq = __fadd_rn(__fadd_rn(__fmul_rn(x, x), __fmul_rn(y, y)),
                         __fmul_rn(z, z));
    xyz4[i] = make_float4(x, y, z, sq);
  }

  const int n = b & 511;         // 0..511
  const float* W1 = (b < 512) ? W1a : W1b;
  short* bhi = (b < 512) ? bhiA : bhiB;
  short* blo = (b < 512) ? bloA : bloB;
  const float v = (n < 256) ? W1[k * DTOK + n]
                            : W1[(259 + k) * DTOK + (n - 256)];
  short h = f2bf(v);
  bhi[n * 256 + k] = h;
  blo[n * 256 + k] = f2bf(v - bf2f(h));
}

// ---------------------------------------------------------------------------
// KNN v11 (R9-exact, best verified 227.99us total): 2 queries/wave,
// LDS-staged pass A (full-set tight threshold) + GLOBAL-STREAMED pass B
// with the serial stable insert. R10 (compact-then-rank) was neutral; R11
// (subset threshold) regressed 2x -- loose thresholds make the pass-B
// taken-branches expose full memory latency (~1.6k cyc per survivor group).
// Tight t (~20 survivors) + branchless-until-survivor streaming is the
// empirical optimum. nbr bit-identical to reference.
// ---------------------------------------------------------------------------
#define KCH 512                     // candidates per staged chunk (pass A)
#define NCH (N_PTS / KCH)           // 16 chunks

__global__ __launch_bounds__(256) void knn_select_kernel(
    const float4* __restrict__ xyz4, int* __restrict__ nbr) {
  __shared__ float4 sA[2][4][64];   // {x0,x1,y0,y1} per pair, 8 KB
  __shared__ float4 sB[2][4][64];   // {z0,z1,w0,w1} per pair, 8 KB
  const int tid = threadIdx.x;
  const int lane = tid & 63;
  const int wave = tid >> 6;
  const int i0 = blockIdx.x * 8 + wave * 2;
  const int i1 = i0 + 1;

  const float4 q0 = xyz4[i0];
  const float4 q1 = xyz4[i1];
  const float2v x02 = {q0.x, q0.x}, y02 = {q0.y, q0.y};
  const float2v z02 = {q0.z, q0.z}, s02 = {q0.w, q0.w};
  const float2v x12 = {q1.x, q1.x}, y12 = {q1.y, q1.y};
  const float2v z12 = {q1.z, q1.z}, s12 = {q1.w, q1.w};
  const float2v n2 = {-2.0f, -2.0f};

  const int ib128 = i0 & ~127;      // uniform: shared 128-block of i0,i1
  const int ih0 = (i0 >> 6) & 1, il0 = i0 & 63;   // uniform
  const int ih1 = (i1 >> 6) & 1, il1 = i1 & 63;   // uniform

  // staging coords: wave w stages pair-group ps=w of each chunk
  const int sgj = wave * 128 + lane;

  // ---- prologue: stage chunk 0 ----
  {
    const float4 c0 = xyz4[sgj];
    const float4 c1 = xyz4[sgj + 64];
    sA[0][wave][lane] = make_float4(c0.x, c1.x, c0.y, c1.y);
    sB[0][wave][lane] = make_float4(c0.z, c1.z, c0.w, c1.w);
  }
  __syncthreads();

  // ---- pass A: per-lane running mins (both queries) over staged chunks ----
  float a00 = FLT_MAX, a01 = FLT_MAX, a10 = FLT_MAX, a11 = FLT_MAX;
  for (int c = 0; c < NCH; ++c) {
    const int b = c & 1;
    float4 nx0, nx1;
    if (c < NCH - 1) {              // issue next-chunk loads early (T14)
      nx0 = xyz4[(c + 1) * KCH + sgj];
      nx1 = xyz4[(c + 1) * KCH + sgj + 64];
    }
    const int cbase = c * KCH;
    #pragma unroll
    for (int ps = 0; ps < 4; ++ps) {
      const float4 a = sA[b][ps][lane];
      const float4 bb = sB[b][ps][lane];
      const float2v px = {a.x, a.y}, py = {a.z, a.w};
      const float2v pz = {bb.x, bb.y}, pw = {bb.z, bb.w};
      const bool selfg = (cbase + ps * 128 == ib128);   // uniform
      const float2v dot0 =
          pk_fma(z02, pz, pk_fma(y02, py, pk_mul(x02, px)));
      float2v d0 = pk_add(pk_fma(n2, dot0, s02), pw);
      const float2v dot1 =
          pk_fma(z12, pz, pk_fma(y12, py, pk_mul(x12, px)));
      float2v d1 = pk_add(pk_fma(n2, dot1, s12), pw);
      if (selfg) {                        // uniform rare branch
        if (lane == il0) {
          if (ih0) d0.y = __fadd_rn(d0.y, 1e10f);
          else     d0.x = __fadd_rn(d0.x, 1e10f);
        }
        if (lane == il1) {
          if (ih1) d1.y = __fadd_rn(d1.y, 1e10f);
          else     d1.x = __fadd_rn(d1.x, 1e10f);
        }
      }
      a00 = fminf(a00, d0.x);
      a01 = fminf(a01, d0.y);
      a10 = fminf(a10, d1.x);
      a11 = fminf(a11, d1.y);
    }
    if (c < NCH - 1) {              // LDS write late; latency hidden
      sA[b ^ 1][wave][lane] = make_float4(nx0.x, nx1.x, nx0.y, nx1.y);
      sB[b ^ 1][wave][lane] = make_float4(nx0.z, nx1.z, nx0.w, nx1.w);
    }
    __syncthreads();
  }

  // ---- two interleaved 64-lane bitonic sorts (ascending) of lane-mins ----
  float v0 = fminf(a00, a01);
  float v1 = fminf(a10, a11);
  #pragma unroll
  for (int k = 2; k <= 64; k <<= 1) {
    #pragma unroll
    for (int j = k >> 1; j > 0; j >>= 1) {
      const float o0 = __shfl_xor(v0, j, 64);
      const float o1 = __shfl_xor(v1, j, 64);
      const bool keepmin = ((lane & k) == 0) == ((lane & j) == 0);
      v0 = keepmin ? fminf(v0, o0) : fmaxf(v0, o0);
      v1 = keepmin ? fminf(v1, o1) : fmaxf(v1, o1);
    }
  }
  const float t0 = __shfl(v0, 15, 64);  // >= true 16th-smallest dist (q0)
  const float t1 = __shfl(v1, 15, 64);  // >= true 16th-smallest dist (q1)

  // ---- pass B: stream DIRECTLY from global (L2-resident), no barriers ----
  float sd0 = FLT_MAX, sd1 = FLT_MAX;   // slot dists (lanes 0..15)
  int sj0 = 0, sj1 = 0;                 // slot indices
  float s150 = FLT_MAX, s151 = FLT_MAX; // running 16th-best (uniform)

  const int gself = i0 >> 6;            // uniform: 64-group holding i0,i1

  float4 pc = xyz4[lane];               // group 0 prefetch
  #pragma unroll 2
  for (int grp = 0; grp < N_PTS / 64; ++grp) {
    float4 pn;
    if (grp < N_PTS / 64 - 1) pn = xyz4[(grp + 1) * 64 + lane];

    // scalar distance chain == pk chain op-for-op (bit-identical)
    const float dot0 = fmaf(q0.z, pc.z, fmaf(q0.y, pc.y,
                                             __fmul_rn(q0.x, pc.x)));
    float d0 = __fadd_rn(__fmaf_rn(-2.0f, dot0, q0.w), pc.w);
    const float dot1 = fmaf(q1.z, pc.z, fmaf(q1.y, pc.y,
                                             __fmul_rn(q1.x, pc.x)));
    float d1 = __fadd_rn(__fmaf_rn(-2.0f, dot1, q1.w), pc.w);
    if (grp == gself) {                 // uniform rare branch
      if (lane == il0) d0 = __fadd_rn(d0, 1e10f);
      if (lane == il1) d1 = __fadd_rn(d1, 1e10f);
    }

    insert_group(d0, grp * 64, t0, lane, sd0, sj0, s150);
    insert_group(d1, grp * 64, t1, lane, sd1, sj1, s151);
    pc = pn;
  }

  if (lane < 16) {
    nbr[i0 * KNN + lane] = sj0;
    nbr[i1 * KNN + lane] = sj1;
  }
}

// ---------------------------------------------------------------------------
// pq GEMM v2 (frozen).
// ---------------------------------------------------------------------------
__global__ __launch_bounds__(256, 2) void pq_gemm_fused_kernel(
    const float* __restrict__ A, const short* __restrict__ Bthi,
    const short* __restrict__ Btlo, const float* __restrict__ xyz,
    const float* __restrict__ W1, const float* __restrict__ b1,
    float* __restrict__ R, float* __restrict__ Q) {
  __shared__ short Ahi[64][32], Alo[64][32];    // 4K + 4K
  __shared__ short Bhi[128][32], Blo[128][32];  // 8K + 8K
  __shared__ float Qs[64][65];                  // 16.6K
  __shared__ float sx[64][3];
  __shared__ float swz[6][64];
  __shared__ float sb1[64];

  const int tid = threadIdx.x;
  const int lane = tid & 63;
  const int wave = tid >> 6;
  const int l15 = lane & 15;
  const int quad = lane >> 4;
  const int mh = wave & 1;
  const int qh = wave >> 1;
  const int m0 = blockIdx.x * 64;
  const int np0 = blockIdx.y * 64;

  if (tid < 64) {
    sx[tid][0] = xyz[(m0 + tid) * 3];
    sx[tid][1] = xyz[(m0 + tid) * 3 + 1];
    sx[tid][2] = xyz[(m0 + tid) * 3 + 2];
  } else if (tid < 128) {
    int n = tid - 64;
    sb1[n] = b1[np0 + n];
    #pragma unroll
    for (int r = 0; r < 3; ++r) {
      swz[r][n] = W1[(256 + r) * DTOK + np0 + n];
      swz[3 + r][n] = W1[(515 + r) * DTOK + np0 + n];
    }
  }

  float4v acc[2][4];
  #pragma unroll
  for (int mf = 0; mf < 2; ++mf)
    #pragma unroll
    for (int nf = 0; nf < 4; ++nf)
      #pragma unroll
      for (int e = 0; e < 4; ++e) acc[mf][nf][e] = 0.f;

  const int ar = tid >> 2;             // A staging row 0..63
  const int ak = (tid & 3) * 8;        // A staging k-offset

  #pragma unroll 1
  for (int kc = 0; kc < 8; ++kc) {
    const int k0 = kc * 32;
    __syncthreads();
    {
      const float* asrc = A + (size_t)(m0 + ar) * 256 + k0 + ak;
      float4 a0 = *(const float4*)asrc;
      float4 a1 = *(const float4*)(asrc + 4);
      float v[8] = {a0.x, a0.y, a0.z, a0.w, a1.x, a1.y, a1.z, a1.w};
      short8 h8, l8;
      #pragma unroll
      for (int e = 0; e < 8; ++e) {
        short h = f2bf(v[e]);
        h8[e] = h;
        l8[e] = f2bf(v[e] - bf2f(h));
      }
      *(short8*)(&Ahi[ar][ak]) = h8;
      *(short8*)(&Alo[ar][ak]) = l8;
    }
    #pragma unroll
    for (int l = 0; l < 4; ++l) {
      const int rem = tid + 256 * (l & 1);
      const int row = rem >> 2;
      const int koff = (rem & 3) * 8;
      const int n = (row < 64) ? (np0 + row) : (256 + np0 + row - 64);
      const short* src = ((l < 2) ? Bthi : Btlo) + (size_t)n * 256 + k0 + koff;
      short8 vv = *(const short8*)src;
      if (l < 2) *(short8*)(&Bhi[row][koff]) = vv;
      else       *(short8*)(&Blo[row][koff]) = vv;
    }
    __syncthreads();

    short8 ah[2], al[2], bh[4], bl[4];
    #pragma unroll
    for (int mf = 0; mf < 2; ++mf) {
      ah[mf] = *(const short8*)(&Ahi[mh * 32 + mf * 16 + l15][quad * 8]);
      al[mf] = *(const short8*)(&Alo[mh * 32 + mf * 16 + l15][quad * 8]);
    }
    #pragma unroll
    for (int nf = 0; nf < 4; ++nf) {
      bh[nf] = *(const short8*)(&Bhi[qh * 64 + nf * 16 + l15][quad * 8]);
      bl[nf] = *(const short8*)(&Blo[qh * 64 + nf * 16 + l15][quad * 8]);
    }
    #pragma unroll
    for (int mf = 0; mf < 2; ++mf)
      #pragma unroll
      for (int nf = 0; nf < 4; ++nf) {
        acc[mf][nf] = __builtin_amdgcn_mfma_f32_16x16x32_bf16(
            ah[mf], bh[nf], acc[mf][nf], 0, 0, 0);
        acc[mf][nf] = __builtin_amdgcn_mfma_f32_16x16x32_bf16(
            ah[mf], bl[nf], acc[mf][nf], 0, 0, 0);
        acc[mf][nf] = __builtin_amdgcn_mfma_f32_16x16x32_bf16(
            al[mf], bh[nf], acc[mf][nf], 0, 0, 0);
      }
  }

  if (qh == 1) {
    #pragma unroll
    for (int mf = 0; mf < 2; ++mf)
      #pragma unroll
      for (int nf = 0; nf < 4; ++nf)
        #pragma unroll
        for (int e = 0; e < 4; ++e) {
          int row = mh * 32 + mf * 16 + quad * 4 + e;
          int col = nf * 16 + l15;
          float q = acc[mf][nf][e] + sx[row][0] * swz[3][col] +
                    sx[row][1] * swz[4][col] + sx[row][2] * swz[5][col];
          Qs[row][col] = q;
          Q[(size_t)(m0 + row) * DTOK + np0 + col] = q;
        }
  }
  __syncthreads();
  if (qh == 0) {
    #pragma unroll
    for (int mf = 0; mf < 2; ++mf)
      #pragma unroll
      for (int nf = 0; nf < 4; ++nf)
        #pragma unroll
        for (int e = 0; e < 4; ++e) {
          int row = mh * 32 + mf * 16 + quad * 4 + e;
          int col = nf * 16 + l15;
          float p = acc[mf][nf][e] + sx[row][0] * swz[0][col] +
                    sx[row][1] * swz[1][col] + sx[row][2] * swz[2][col];
          R[(size_t)(m0 + row) * DTOK + np0 + col] =
              (p + sb1[col]) - Qs[row][col];
        }
  }
}

// ---------------------------------------------------------------------------
// EdgeConv via MFMA (frozen R10 version).
// ---------------------------------------------------------------------------
#define EP 8          // points per group

__global__ __launch_bounds__(256, 2) void edge_mfma_kernel(
    const float* __restrict__ R, const float* __restrict__ Q,
    const int* __restrict__ nbr, const float* __restrict__ W2,
    const float* __restrict__ b2, float* __restrict__ out,
    int num_groups, int groups_per_block) {
  __shared__ short Hs[EP * KNN * DTOK];   // 128 rows x 256, 64 KB
  const int lane = threadIdx.x & 63;
  const int wave = threadIdx.x >> 6;
  const int l15 = lane & 15;
  const int quad = lane >> 4;

  short8 bfr[4][8];
  #pragma unroll
  for (int nt_i = 0; nt_i < 4; ++nt_i) {
    const int n = (wave * 4 + nt_i) * 16 + l15;
    #pragma unroll
    for (int kt = 0; kt < 8; ++kt) {
      short8 f;
      #pragma unroll
      for (int jj = 0; jj < 8; ++jj) {
        int k = kt * 32 + quad * 8 + jj;
        f[jj] = f2bf(W2[k * DTOK + n]);
      }
      bfr[nt_i][kt] = f;
    }
  }

  const int wc8 = lane >> 1;
  const int wsub = (lane & 1) * 4;

  for (int gi = 0; gi < groups_per_block; ++gi) {
    const int g = blockIdx.x + gi * gridDim.x;
    if (g >= num_groups) break;
    const int i0 = g * EP;

    // ---- build H: prefetched nbr via lane reg + shfl, pipelined gathers ----
    {
      const int ia = i0 + wave * 2;
      const int jr0 = nbr[ia * KNN + l15];
      const int jr1 = nbr[(ia + 1) * KNN + l15];
      const float4 ri0 = ((const float4*)(R + (size_t)ia * DTOK))[lane];
      const float4 ri1 = ((const float4*)(R + (size_t)(ia + 1) * DTOK))[lane];
      #pragma unroll
      for (int pp = 0; pp < 2; ++pp) {
        const float4 ri = pp ? ri1 : ri0;
        const int jr = pp ? jr1 : jr0;
        #pragma unroll
        for (int k = 0; k < KNN; ++k) {
          const int j = __shfl(jr, k, 16);
          const float4 qj = ((const float4*)(Q + (size_t)j * DTOK))[lane];
          const int r = wave * 32 + pp * 16 + k;
          uint2 pk;
          pk.x = ((unsigned)(unsigned short)f2bf(fmaxf(ri.x + qj.x, 0.f))) |
                 (((unsigned)(unsigned short)f2bf(fmaxf(ri.y + qj.y, 0.f))) << 16);
          pk.y = ((unsigned)(unsigned short)f2bf(fmaxf(ri.z + qj.z, 0.f))) |
                 (((unsigned)(unsigned short)f2bf(fmaxf(ri.w + qj.w, 0.f))) << 16);
          *(uint2*)(&Hs[r * DTOK + ((wc8 ^ (r & 7)) << 3) + wsub]) = pk;
        }
      }
    }
    __syncthreads();

    #pragma unroll
    for (int mp = 0; mp < 4; ++mp) {
      float4v acc[2][4];
      #pragma unroll
      for (int mi = 0; mi < 2; ++mi)
        #pragma unroll
        for (int nt_i = 0; nt_i < 4; ++nt_i)
          #pragma unroll
          for (int e = 0; e < 4; ++e) acc[mi][nt_i][e] = 0.f;

      #pragma unroll
      for (int kt = 0; kt < 8; ++kt) {
        const int pc = ((kt * 4 + quad) ^ (l15 & 7)) << 3;
        const short8 a0 = *(const short8*)(
            &Hs[((mp * 2 + 0) * 16 + l15) * DTOK + pc]);
        const short8 a1 = *(const short8*)(
            &Hs[((mp * 2 + 1) * 16 + l15) * DTOK + pc]);
        #pragma unroll
        for (int nt_i = 0; nt_i < 4; ++nt_i) {
          acc[0][nt_i] = __builtin_amdgcn_mfma_f32_16x16x32_bf16(
              a0, bfr[nt_i][kt], acc[0][nt_i], 0, 0, 0);
          acc[1][nt_i] = __builtin_amdgcn_mfma_f32_16x16x32_bf16(
              a1, bfr[nt_i][kt], acc[1][nt_i], 0, 0, 0);
        }
      }

      #pragma unroll
      for (int mi = 0; mi < 2; ++mi) {
        #pragma unroll
        for (int nt_i = 0; nt_i < 4; ++nt_i) {
          float rm = fmaxf(fmaxf(acc[mi][nt_i][0], acc[mi][nt_i][1]),
                           fmaxf(acc[mi][nt_i][2], acc[mi][nt_i][3]));
          rm = fmaxf(rm, __shfl_xor(rm, 16, 64));
          rm = fmaxf(rm, __shfl_xor(rm, 32, 64));
          if (lane < 16) {
            const int i = i0 + mp * 2 + mi;
            const int n = (wave * 4 + nt_i) * 16 + lane;
            out[(size_t)i * DTOK + n] = rm + b2[n];
          }
        }
      }
    }
    __syncthreads();
  }
}

// ---------------------------------------------------------------------------
extern "C" void kernel_launch(void* const* d_in, const int* in_sizes, int n_in,
                              void* d_out, int out_size, void* d_ws,
                              size_t ws_size, hipStream_t stream) {
  const float* xyz = (const float*)d_in[0];
  const float* feat = (const float*)d_in[1];
  const float* W1a = (const float*)d_in[2];
  const float* b1a = (const float*)d_in[3];
  const float* W2a = (const float*)d_in[4];
  const float* b2a = (const float*)d_in[5];
  const float* W1b = (const float*)d_in[6];
  const float* b1b = (const float*)d_in[7];
  const float* W2b = (const float*)d_in[8];
  const float* b2b = (const float*)d_in[9];
  float* out = (float*)d_out;

  // ws layout (~25 MB): nbr 0.5 | xyz4 128KB | Bt_b @w1+1MB (512KB, in the
  // free w1+[128KB,8MB) gap) | R @w1+8MB | Q @w1+16MB | Bt_a @w1+24MB
  char* w = (char*)d_ws;
  const size_t SZ_NBR = (size_t)N_PTS * KNN * sizeof(int);        // 512 KB
  const size_t MB = 1024 * 1024;
  int* nbr = (int*)w;
  char* w1 = w + SZ_NBR;
  float4* xyz4 = (float4*)w1;                  // 128 KB
  short* BthiB = (short*)(w1 + 1 * MB);        // 256 KB (free region)
  short* BtloB = BthiB + 512 * 256;            // 256 KB
  float* R = (float*)(w1 + 8 * MB);            // 8 MB
  float* Q = (float*)(w1 + 16 * MB);           // 8 MB
  short* BthiA = (short*)(w1 + 24 * MB);       // 256 KB
  short* BtloA = BthiA + 512 * 256;            // 256 KB
  float* bufC = out;                           // layer-a output staging

  const int num_groups = N_PTS / EP;           // 1024
  const int nblocks = 512;

  // merged prologue: xyz4 prep + both weight conversions (one dispatch)
  prep_convert_kernel<<<1024, 256, 0, stream>>>(
      xyz, xyz4, W1a, BthiA, BtloA, W1b, BthiB, BtloB);

  knn_select_kernel<<<N_PTS / 8, 256, 0, stream>>>(xyz4, nbr);

  // layer a
  pq_gemm_fused_kernel<<<dim3(N_PTS / 64, 4), 256, 0, stream>>>(
      feat, BthiA, BtloA, xyz, W1a, b1a, R, Q);
  edge_mfma_kernel<<<nblocks, 256, 0, stream>>>(R, Q, nbr, W2a, b2a, bufC,
                                                num_groups, 2);

  // layer b
  pq_gemm_fused_kernel<<<dim3(N_PTS / 64, 4), 256, 0, stream>>>(
      bufC, BthiB, BtloB, xyz, W1b, b1b, R, Q);
  edge_mfma_kernel<<<nblocks, 256, 0, stream>>>(R, Q, nbr, W2b, b2b, out,
                                                num_groups, 2);
}